// Round 9
// baseline (610.587 us; speedup 1.0000x reference)
//
#include <hip/hip_runtime.h>
#include <cstddef>

#define DIM   1024
#define NH    16
#define HD    64
#define LXX   2048
#define LCC   4096
#define HID   2816
#define RTOT  6144
#define QKVW  3072

typedef unsigned int   uint32;
typedef unsigned short u16;
typedef __attribute__((ext_vector_type(8))) __bf16 bf16x8;
typedef __attribute__((ext_vector_type(4))) float  f32x4;

typedef __attribute__((address_space(1))) unsigned int as1_u32;
typedef __attribute__((address_space(3))) unsigned int as3_u32;

__device__ __forceinline__ u16 f2bf(float f) {
    union { float f; uint32 u; } c; c.f = f;
    uint32 u = c.u;
    return (u16)((u + 0x7fffu + ((u >> 16) & 1u)) >> 16);   // RNE
}
__device__ __forceinline__ float bf2f(u16 h) {
    union { uint32 u; float f; } c; c.u = ((uint32)h) << 16;
    return c.f;
}
__device__ __forceinline__ float fast_exp2(float x) {      // v_exp_f32 = 2^x
    float r;
    asm("v_exp_f32 %0, %1" : "=v"(r) : "v"(x));
    return r;
}
__device__ __forceinline__ uint32 cvt_pk_bf16(float lo, float hi) {
    uint32 r;
    asm("v_cvt_pk_bf16_f32 %0, %1, %2" : "=v"(r) : "v"(lo), "v"(hi));
    return r;
}
// async 16B global -> LDS (wave-uniform LDS base + lane*16)
__device__ __forceinline__ void gload16(const u16* g, u16* l) {
    __builtin_amdgcn_global_load_lds((as1_u32*)(void*)g, (as3_u32*)l, 16, 0, 0);
}

// ---------------------------------------------------------------------------
// LayerNorm (fp32 in -> bf16 out). Two-source: row<split from in1 else in2.
// ---------------------------------------------------------------------------
__global__ __launch_bounds__(256) void ln_bf16_kernel(const float* __restrict__ in1,
                                                      const float* __restrict__ in2,
                                                      int split,
                                                      const float* __restrict__ g,
                                                      const float* __restrict__ b,
                                                      u16* __restrict__ out) {
    int row = blockIdx.x;
    const float* x = (row < split) ? in1 + (size_t)row * DIM
                                   : in2 + (size_t)(row - split) * DIM;
    u16* o = out + (size_t)row * DIM;
    int t = threadIdx.x;

    float v0 = x[t], v1 = x[t + 256], v2 = x[t + 512], v3 = x[t + 768];
    float s  = v0 + v1 + v2 + v3;
    float sq = v0 * v0 + v1 * v1 + v2 * v2 + v3 * v3;
    for (int off = 32; off; off >>= 1) {
        s  += __shfl_down(s, off);
        sq += __shfl_down(sq, off);
    }
    __shared__ float rs[4], rq[4];
    __shared__ float mean_s, rstd_s;
    int wid = t >> 6, lane = t & 63;
    if (lane == 0) { rs[wid] = s; rq[wid] = sq; }
    __syncthreads();
    if (t == 0) {
        float S = rs[0] + rs[1] + rs[2] + rs[3];
        float Q = rq[0] + rq[1] + rq[2] + rq[3];
        float m = S / (float)DIM;
        float var = Q / (float)DIM - m * m;
        mean_s = m;
        rstd_s = rsqrtf(var + 1e-5f);
    }
    __syncthreads();
    float m = mean_s, r = rstd_s;
    o[t]       = f2bf((v0 - m) * r * g[t]       + b[t]);
    o[t + 256] = f2bf((v1 - m) * r * g[t + 256] + b[t + 256]);
    o[t + 512] = f2bf((v2 - m) * r * g[t + 512] + b[t + 512]);
    o[t + 768] = f2bf((v3 - m) * r * g[t + 768] + b[t + 768]);
}

// ---------------------------------------------------------------------------
// All 5 weight transposes (fp32 [R][C] -> bf16 [C][R]) in one dispatch.
// ---------------------------------------------------------------------------
__global__ __launch_bounds__(256) void transpose_all(const float* __restrict__ qkv_w,
                                                     const float* __restrict__ out_w,
                                                     const float* __restrict__ w1,
                                                     const float* __restrict__ w3,
                                                     const float* __restrict__ w2,
                                                     u16* __restrict__ t_qkv,
                                                     u16* __restrict__ t_out,
                                                     u16* __restrict__ t_w1,
                                                     u16* __restrict__ t_w3,
                                                     u16* __restrict__ t_w2) {
    int bid = blockIdx.x;
    const float* in; u16* op; int R, C;
    if (bid < 3072)      { in = qkv_w; op = t_qkv; R = 1024; C = 3072; }
    else if (bid < 4096) { in = out_w; op = t_out; R = 1024; C = 1024; bid -= 3072; }
    else if (bid < 6912) { in = w1;    op = t_w1;  R = 1024; C = 2816; bid -= 4096; }
    else if (bid < 9728) { in = w3;    op = t_w3;  R = 1024; C = 2816; bid -= 6912; }
    else                 { in = w2;    op = t_w2;  R = 2816; C = 1024; bid -= 9728; }
    int nbx = C / 32;
    int c0 = (bid % nbx) * 32, r0 = (bid / nbx) * 32;

    __shared__ float tile[32][33];
    int tx = threadIdx.x & 31, ty = threadIdx.x >> 5;   // 32 x 8
#pragma unroll
    for (int i = 0; i < 32; i += 8)
        tile[ty + i][tx] = in[(size_t)(r0 + ty + i) * C + c0 + tx];
    __syncthreads();
#pragma unroll
    for (int i = 0; i < 32; i += 8)
        op[(size_t)(c0 + ty + i) * R + r0 + tx] = f2bf(tile[tx][ty + i]);
}

// ---------------------------------------------------------------------------
// bf16 MFMA GEMM v3 — m97 config: BK=64, global_load_lds(16B) into linear
// LDS with both-sides XOR swizzle, 2-barrier K-loop.
// C[M,N] = A[M,K] @ Bt[N,K]^T. Tile TM x 128, 256 threads (4 waves).
// RESMODE: 0 none; 1 += res fp32; 2 += row<LXX ? res : resB (split);
//          3 out = silu(res_bf16) * acc  (FFN w3+silu fusion).
// ---------------------------------------------------------------------------
template <int TM, bool OUTBF, bool BIAS, int RESMODE>
__global__ __launch_bounds__(256) void gemm3(const u16* __restrict__ A,
                                             const u16* __restrict__ Bt,
                                             const float* __restrict__ bias,
                                             const void* __restrict__ res,
                                             const float* __restrict__ resB,
                                             void* __restrict__ Cout,
                                             int M, int N, int K) {
    constexpr int MI = TM / 32;             // m-fragments per wave (4 or 2)
    __shared__ u16 As[TM * 64];             // logical [TM][64], slot-swizzled
    __shared__ u16 Bs[128 * 64];
    int m0 = blockIdx.y * TM, n0 = blockIdx.x * 128;
    int t = threadIdx.x, lane = t & 63, w = t >> 6;
    int wr = (w >> 1) * (TM / 2), wc = (w & 1) * 64;
    int r = lane & 15, g = lane >> 4;

    // staging: thread t fetches row 32*s+(t>>3), PRE-SWIZZLED col-block
    // (t&7)^((t>>3)&7); HW writes LDS linearly at t*16B -> slot c^(row&7).
    int trow = t >> 3;
    int tcb  = (t & 7) ^ (trow & 7);
    const u16* ga = A  + (size_t)(m0 + trow) * K + tcb * 8;
    const u16* gb = Bt + (size_t)(n0 + trow) * K + tcb * 8;

    f32x4 acc[MI][4] = {};

    for (int k0 = 0; k0 < K; k0 += 64) {
#pragma unroll
        for (int s = 0; s < TM / 32; s++)
            gload16(ga + (size_t)(32 * s) * K + k0, &As[s * 2048 + w * 512]);
#pragma unroll
        for (int s = 0; s < 4; s++)
            gload16(gb + (size_t)(32 * s) * K + k0, &Bs[s * 2048 + w * 512]);
        __syncthreads();                     // drains vmcnt: LDS populated
#pragma unroll
        for (int kk = 0; kk < 2; kk++) {
            bf16x8 af[MI], bfv[4];
#pragma unroll
            for (int i = 0; i < MI; i++)
                af[i] = *(const bf16x8*)&As[(wr + i * 16 + r) * 64 + (((kk * 4 + g) ^ (r & 7)) * 8)];
#pragma unroll
            for (int i = 0; i < 4; i++)
                bfv[i] = *(const bf16x8*)&Bs[(wc + i * 16 + r) * 64 + (((kk * 4 + g) ^ (r & 7)) * 8)];
#pragma unroll
            for (int mi = 0; mi < MI; mi++)
#pragma unroll
                for (int ni = 0; ni < 4; ni++)
                    acc[mi][ni] = __builtin_amdgcn_mfma_f32_16x16x32_bf16(
                        af[mi], bfv[ni], acc[mi][ni], 0, 0, 0);
        }
        __syncthreads();                     // reads done before re-stage
    }
#pragma unroll
    for (int mi = 0; mi < MI; mi++)
#pragma unroll
        for (int ni = 0; ni < 4; ni++)
#pragma unroll
            for (int j = 0; j < 4; j++) {
                int row = m0 + wr + mi * 16 + g * 4 + j;
                int col = n0 + wc + ni * 16 + r;
                float v = acc[mi][ni][j];
                if (BIAS) v += bias[col];
                if (RESMODE == 1) v += ((const float*)res)[(size_t)row * N + col];
                if (RESMODE == 2) v += (row < LXX)
                        ? ((const float*)res)[(size_t)row * N + col]
                        : resB[(size_t)(row - LXX) * N + col];
                if (RESMODE == 3) {
                    float uv = bf2f(((const u16*)res)[(size_t)row * N + col]);
                    v = (uv / (1.f + __expf(-uv))) * v;
                }
                if (OUTBF) ((u16*)Cout)[(size_t)row * N + col] = f2bf(v);
                else       ((float*)Cout)[(size_t)row * N + col] = v;
            }
}

// ---------------------------------------------------------------------------
// RoPE in place on bf16 QKV buffer. q columns pre-scaled by log2(e)/sqrt(HD)
// so attention scores live in the log2 domain (p = v_exp_f32(s)).
// ---------------------------------------------------------------------------
__global__ __launch_bounds__(256) void rope_bf16(u16* __restrict__ p,
                                                 const int* __restrict__ xpos,
                                                 const int* __restrict__ opos) {
    int row = blockIdx.x;
    int t = threadIdx.x;
    float pos = (row < LXX) ? (float)(*xpos + row) : (float)(*opos + (row - LXX));
    u16* pr = p + (size_t)row * QKVW;
#pragma unroll
    for (int i = 0; i < 4; i++) {
        int pi = t + i * 256;               // pair index 0..1023
        int sec = pi >> 9, rest = pi & 511, head = rest >> 5, j = rest & 31;
        int col = sec * 1024 + head * 64 + j;
        float inv = exp2f(-0.41524101186092034f * (float)j);  // 10000^(-2j/64)
        float ang = pos * inv;
        float sn, cs;
        __sincosf(ang, &sn, &cs);
        float mul = (sec == 0) ? 0.18033688f : 1.0f;          // 0.125*log2(e)
        float t1 = bf2f(pr[col]), t2 = bf2f(pr[col + 32]);
        pr[col]      = f2bf((t1 * cs - t2 * sn) * mul);
        pr[col + 32] = f2bf((t2 * cs + t1 * sn) * mul);
    }
}

// ---------------------------------------------------------------------------
// MFMA flash attention v6: KVBLK=128 (halved barrier/staging rate), swapped
// QK^T, max-free exp2 softmax, cvt_pk packing, reg-resident P.
// Grid (LQ/64, NH), 256 thr (4 waves x 16 q-rows). 32 KiB LDS.
// K in Ks[128][64] (XOR sw on 16B col pairs); V in Vt[64][128] (block-XOR
// on 8-u16 k-blocks: kblk ^= d&7) -> all b128 at the 8-lane/4-bank floor.
// MERGED: q0>=LXX uses Q2, stores bf16 to Ob; else fp32 to Of.
// RMW: read Of (fp32), add own result, store bf16 to Ob.
// ---------------------------------------------------------------------------
template <int CAUSAL, int MERGED, int RMW>
__global__ __launch_bounds__(256) void attn_v6(const u16* __restrict__ Q1,
                                               const u16* __restrict__ Q2,
                                               const u16* __restrict__ Kb,
                                               const u16* __restrict__ Vb,
                                               float* __restrict__ Of,
                                               u16* __restrict__ Ob,
                                               int LK) {
    __shared__ u16 Ks[128 * 64];
    __shared__ u16 Vt[64 * 128];
    int h = blockIdx.y;
    int q0 = blockIdx.x * 64;
    const u16* Qb = Q1;
    bool second = false;
    if (MERGED && q0 >= LXX) { Qb = Q2; second = true; q0 -= LXX; }
    int t = threadIdx.x, lane = t & 63, w = t >> 6;
    int r = lane & 15, g = lane >> 4;
    int hHD = h * HD;

    const u16* qp = Qb + (size_t)(q0 + w * 16 + r) * QKVW + hHD + g * 8;
    bf16x8 qf0 = *(const bf16x8*)qp;
    bf16x8 qf1 = *(const bf16x8*)(qp + 32);

    // staging coords: K rows kr & kr+64 (4 thr/row); V via u32 dim-pairs
    int kr = t >> 2, c0 = (t & 3) * 16;
    const u16* kg_ = Kb + hHD + c0;
    int d0 = (t & 31) * 2, kb = (t >> 5) * 8;
    const u16* vg = Vb + hHD + d0;
    int swk = ((kr >> 1) & 7) << 3;
    int vs0 = ((kb >> 3) ^ (d0 & 7)) * 8;          // V slot, row d0
    int vs1 = ((kb >> 3) ^ ((d0 + 1) & 7)) * 8;    // V slot, row d0+1

    f32x4 o[4] = {};
    float l_run = 0.f;

    int nt = CAUSAL ? ((q0 + 64 + 127) >> 7) : (LK >> 7);

    bf16x8 ka0, ka1, ka2, ka3;
    uint32 vv[16];
    {
        size_t krow = (size_t)kr * QKVW;
        size_t krow2 = (size_t)(kr + 64) * QKVW;
        ka0 = *(const bf16x8*)(kg_ + krow);
        ka1 = *(const bf16x8*)(kg_ + krow + 8);
        ka2 = *(const bf16x8*)(kg_ + krow2);
        ka3 = *(const bf16x8*)(kg_ + krow2 + 8);
#pragma unroll
        for (int kk = 0; kk < 8; kk++) {
            vv[kk]     = *(const uint32*)(vg + (size_t)(kb + kk) * QKVW);
            vv[kk + 8] = *(const uint32*)(vg + (size_t)(kb + 64 + kk) * QKVW);
        }
    }

    for (int kt = 0; kt < nt; kt++) {
        int k0 = kt * 128;
        __syncthreads();
        // ---- stage tile (all b128, swizzled) ----
        *(bf16x8*)&Ks[kr * 64 + (c0 ^ swk)]              = ka0;
        *(bf16x8*)&Ks[kr * 64 + ((c0 + 8) ^ swk)]        = ka1;
        *(bf16x8*)&Ks[(kr + 64) * 64 + (c0 ^ swk)]       = ka2;
        *(bf16x8*)&Ks[(kr + 64) * 64 + ((c0 + 8) ^ swk)] = ka3;
        {
            uint4 lo4, hi4, lo4b, hi4b;
            lo4.x  = __builtin_amdgcn_perm(vv[1],  vv[0],  0x05040100);
            lo4.y  = __builtin_amdgcn_perm(vv[3],  vv[2],  0x05040100);
            lo4.z  = __builtin_amdgcn_perm(vv[5],  vv[4],  0x05040100);
            lo4.w  = __builtin_amdgcn_perm(vv[7],  vv[6],  0x05040100);
            hi4.x  = __builtin_amdgcn_perm(vv[1],  vv[0],  0x07060302);
            hi4.y  = __builtin_amdgcn_perm(vv[3],  vv[2],  0x07060302);
            hi4.z  = __builtin_amdgcn_perm(vv[5],  vv[4],  0x07060302);
            hi4.w  = __builtin_amdgcn_perm(vv[7],  vv[6],  0x07060302);
            lo4b.x = __builtin_amdgcn_perm(vv[9],  vv[8],  0x05040100);
            lo4b.y = __builtin_amdgcn_perm(vv[11], vv[10], 0x05040100);
            lo4b.z = __builtin_amdgcn_perm(vv[13], vv[12], 0x05040100);
            lo4b.w = __builtin_amdgcn_perm(vv[15], vv[14], 0x05040100);
            hi4b.x = __builtin_amdgcn_perm(vv[9],  vv[8],  0x07060302);
            hi4b.y = __builtin_amdgcn_perm(vv[11], vv[10], 0x07060302);
            hi4b.z = __builtin_amdgcn_perm(vv[13], vv[12], 0x07060302);
            hi4b.w = __builtin_amdgcn_perm(vv[15], vv[14], 0x07060302);
            *(uint4*)&Vt[d0 * 128 + vs0]            = lo4;
            *(uint4*)&Vt[(d0 + 1) * 128 + vs1]      = hi4;
            *(uint4*)&Vt[d0 * 128 + vs0 + 64]       = lo4b;   // keys +64
            *(uint4*)&Vt[(d0 + 1) * 128 + vs1 + 64] = hi4b;
        }
        __syncthreads();
        // ---- prefetch next tile ----
        if (kt + 1 < nt) {
            int kn = k0 + 128;
            size_t krow = (size_t)(kn + kr) * QKVW;
            size_t krow2 = (size_t)(kn + kr + 64) * QKVW;
            ka0 = *(const bf16x8*)(kg_ + krow);
            ka1 = *(const bf16x8*)(kg_ + krow + 8);
            ka2 = *(const bf16x8*)(kg_ + krow2);
            ka3 = *(const bf16x8*)(kg_ + krow2 + 8);
#pragma unroll
            for (int kk = 0; kk < 8; kk++) {
                vv[kk]     = *(const uint32*)(vg + (size_t)(kn + kb + kk) * QKVW);
                vv[kk + 8] = *(const uint32*)(vg + (size_t)(kn + kb + 64 + kk) * QKVW);
            }
        }
        // ---- S^T = K @ Q^T (log2 domain) + max-free softmax + pack ----
        uint32 pk[8][2];
        float lt = 0.f;
        int qrow = q0 + w * 16 + r;
#pragma unroll
        for (int f = 0; f < 8; f++) {
            int row = f * 16 + r;
            int sw = ((row >> 1) & 7) << 3;
            bf16x8 klo = *(const bf16x8*)&Ks[row * 64 + ((g * 8) ^ sw)];
            bf16x8 khi = *(const bf16x8*)&Ks[row * 64 + ((32 + g * 8) ^ sw)];
            __builtin_amdgcn_s_setprio(1);
            f32x4 z = {};
            z = __builtin_amdgcn_mfma_f32_16x16x32_bf16(klo, qf0, z, 0, 0, 0);
            z = __builtin_amdgcn_mfma_f32_16x16x32_bf16(khi, qf1, z, 0, 0, 0);
            __builtin_amdgcn_s_setprio(0);
            float p_[4];
#pragma unroll
            for (int j = 0; j < 4; j++) {
                float sv = z[j];
                if (CAUSAL && kt == nt - 1)
                    if (k0 + f * 16 + g * 4 + j > qrow) sv = -1e30f;
                p_[j] = fast_exp2(sv);
                lt += p_[j];
            }
            pk[f][0] = cvt_pk_bf16(p_[0], p_[1]);
            pk[f][1] = cvt_pk_bf16(p_[2], p_[3]);
        }
        l_run += lt;                        // per-lane partial; reduced at end
        // ---- redistribute P^T (C/D layout) -> P A-frags (4 x 32 keys) ----
        bf16x8 pa[4];
#pragma unroll
        for (int kg2 = 0; kg2 < 4; kg2++) {
            union { uint32 u[4]; bf16x8 v; } pc;
#pragma unroll
            for (int c = 0; c < 4; c++) {
                int srcl = r + 16 * (2 * (g & 1) + (c >> 1));
                uint32 alo = (uint32)__shfl((int)pk[2 * kg2][c & 1], srcl, 64);
                uint32 ahi = (uint32)__shfl((int)pk[2 * kg2 + 1][c & 1], srcl, 64);
                pc.u[c] = (g & 2) ? ahi : alo;
            }
            pa[kg2] = pc.v;
        }
        // ---- O += P @ V ----
        __builtin_amdgcn_s_setprio(1);
#pragma unroll
        for (int df = 0; df < 4; df++) {
            int row = df * 16 + r;
            int sv = row & 7;
#pragma unroll
            for (int kg2 = 0; kg2 < 4; kg2++) {
                bf16x8 vf = *(const bf16x8*)&Vt[row * 128 + (((kg2 * 4 + g) ^ sv) * 8)];
                o[df] = __builtin_amdgcn_mfma_f32_16x16x32_bf16(pa[kg2], vf, o[df], 0, 0, 0);
            }
        }
        __builtin_amdgcn_s_setprio(0);
    }

    // ---- epilogue: reduce l across k-groups, normalize, store ----
    l_run += __shfl_xor(l_run, 16, 64);
    l_run += __shfl_xor(l_run, 32, 64);
    float lb[4];
#pragma unroll
    for (int j = 0; j < 4; j++) lb[j] = __shfl(l_run, (lane >> 4) * 4 + j, 64);
#pragma unroll
    for (int j = 0; j < 4; j++) lb[j] = 1.0f / lb[j];
#pragma unroll
    for (int df = 0; df < 4; df++)
#pragma unroll
        for (int j = 0; j < 4; j++) {
            float val = o[df][j] * lb[j];
            int row = q0 + w * 16 + g * 4 + j;
            int col = hHD + df * 16 + r;
            size_t idx = (size_t)row * DIM + col;
            if (MERGED) {
                if (second) Ob[idx] = f2bf(val);
                else        Of[idx] = val;
            } else if (RMW) {
                Ob[idx] = f2bf(val + Of[idx]);
            } else {
                Of[idx] = val;
            }
        }
}

// ---------------------------------------------------------------------------
// Orchestration
// ---------------------------------------------------------------------------
extern "C" void kernel_launch(void* const* d_in, const int* in_sizes, int n_in,
                              void* d_out, int out_size, void* d_ws, size_t ws_size,
                              hipStream_t stream) {
    const float* x     = (const float*)d_in[0];
    const float* ctx   = (const float*)d_in[1];
    const float* qkv_w = (const float*)d_in[2];
    const float* qkv_b = (const float*)d_in[3];
    const float* out_w = (const float*)d_in[4];
    const float* out_b = (const float*)d_in[5];
    const float* w1    = (const float*)d_in[6];
    const float* w3    = (const float*)d_in[7];
    const float* w2    = (const float*)d_in[8];
    const float* n1_g  = (const float*)d_in[9];
    const float* n1_b  = (const float*)d_in[10];
    const float* n2_g  = (const float*)d_in[11];
    const float* n2_b  = (const float*)d_in[12];
    const int*   ocp   = (const int*)d_in[13];
    const int*   xpos  = (const int*)d_in[15];

    float* out = (float*)d_out;                 // [4096][1024] fp32 (x_out|c_out)

    // workspace layout (u16 units) — ~93 MB total
    u16* wsp    = (u16*)d_ws;
    u16* wt_qkv = wsp;                                  // 3,145,728
    u16* wt_out = wt_qkv + (size_t)3072 * 1024;         // 1,048,576
    u16* wt_w1  = wt_out + (size_t)1024 * 1024;         // 2,883,584
    u16* wt_w3  = wt_w1  + (size_t)2816 * 1024;
    u16* wt_w2  = wt_w3  + (size_t)2816 * 1024;
    u16* lnbuf  = wt_w2  + (size_t)1024 * 2816;         // 6,291,456  [6144][1024]
    u16* qkvbf  = lnbuf  + (size_t)RTOT * DIM;          // 18,874,368 [6144][3072]
    float* attn_x = (float*)(qkvbf + (size_t)RTOT * QKVW);  // 2048*1024 fp32
    u16* h2_bf  = (u16*)(attn_x + (size_t)LXX * DIM);   // 4,194,304  [4096][1024]
    // aliases over dead regions
    u16* ax_bf = lnbuf;                          // [2048][1024], after QKV gemm
    u16* ac_bf = lnbuf + (size_t)LXX * DIM;      // contiguous with ax -> [4096][1024]
    u16* u_bf  = qkvbf;                          // [4096][2816], after attention
    u16* v_bf  = qkvbf + (size_t)4096 * HID;     // spills exactly into attn_x region

    // 1. all weight transposes, one dispatch
    transpose_all<<<12544, 256, 0, stream>>>(qkv_w, out_w, w1, w3, w2,
                                             wt_qkv, wt_out, wt_w1, wt_w3, wt_w2);

    // 2. LN1 over x|ctx -> bf16 [6144][1024]
    ln_bf16_kernel<<<RTOT, 256, 0, stream>>>(x, ctx, LXX, n1_g, n1_b, lnbuf);

    // 3. fused QKV GEMM -> bf16
    gemm3<128, true, true, 0><<<dim3(QKVW / 128, RTOT / 128), 256, 0, stream>>>(
        lnbuf, wt_qkv, qkv_b, nullptr, nullptr, qkvbf, RTOT, QKVW, DIM);

    // 4. RoPE in place (q columns pre-scaled by 0.125*log2e)
    rope_bf16<<<RTOT, 256, 0, stream>>>(qkvbf, xpos, ocp);

    const u16* Qx = qkvbf;
    const u16* Kx = qkvbf + 1024;
    const u16* Vx = qkvbf + 2048;
    const u16* Kc = qkvbf + (size_t)LXX * QKVW + 1024;
    const u16* Vc = qkvbf + (size_t)LXX * QKVW + 2048;
    const u16* Qs = qkvbf + (size_t)(LXX + 2048) * QKVW;

    // 5. attentions: merged a1+a3 (a3 -> ac_bf direct); causal a2 RMW -> ax_bf
    attn_v6<0, 1, 0><<<dim3((LXX + 2048) / 64, NH), 256, 0, stream>>>(
        Qx, Qs, Kc, Vc, attn_x, ac_bf, LCC);
    attn_v6<1, 0, 1><<<dim3(LXX / 64, NH), 256, 0, stream>>>(
        Qx, nullptr, Kx, Vx, attn_x, ax_bf, LXX);

    // 6. merged out-proj: [4096][1024] attn @ out_w + bias + split residual -> out
    gemm3<128, false, true, 2><<<dim3(DIM / 128, 4096 / 128), 256, 0, stream>>>(
        ax_bf, wt_out, out_b, x, ctx + (size_t)2048 * DIM, out, 4096, DIM, DIM);

    // 7. merged FFN over both streams (M=4096); silu fused into w3 epilogue
    ln_bf16_kernel<<<4096, 256, 0, stream>>>(out, out, 4096, n2_g, n2_b, h2_bf);
    gemm3<128, true, false, 0><<<dim3(HID / 128, 4096 / 128), 256, 0, stream>>>(
        h2_bf, wt_w1, nullptr, nullptr, nullptr, u_bf, 4096, HID, DIM);
    gemm3<128, true, false, 3><<<dim3(HID / 128, 4096 / 128), 256, 0, stream>>>(
        h2_bf, wt_w3, nullptr, u_bf, nullptr, v_bf, 4096, HID, DIM);
    gemm3<128, false, false, 1><<<dim3(DIM / 128, 4096 / 128), 256, 0, stream>>>(
        v_bf, wt_w2, nullptr, out, nullptr, out, 4096, DIM, HID);
}

// Round 10
// 521.428 us; speedup vs baseline: 1.1710x; 1.1710x over previous
//
#include <hip/hip_runtime.h>
#include <cstddef>

#define DIM   1024
#define NH    16
#define HD    64
#define LXX   2048
#define LCC   4096
#define HID   2816
#define RTOT  6144
#define QKVW  3072

typedef unsigned int   uint32;
typedef unsigned short u16;
typedef __attribute__((ext_vector_type(8))) __bf16 bf16x8;
typedef __attribute__((ext_vector_type(4))) float  f32x4;

typedef __attribute__((address_space(1))) unsigned int as1_u32;
typedef __attribute__((address_space(3))) unsigned int as3_u32;

__device__ __forceinline__ u16 f2bf(float f) {
    union { float f; uint32 u; } c; c.f = f;
    uint32 u = c.u;
    return (u16)((u + 0x7fffu + ((u >> 16) & 1u)) >> 16);   // RNE
}
__device__ __forceinline__ float bf2f(u16 h) {
    union { uint32 u; float f; } c; c.u = ((uint32)h) << 16;
    return c.f;
}
__device__ __forceinline__ float fast_exp2(float x) {      // v_exp_f32 = 2^x
    float r;
    asm("v_exp_f32 %0, %1" : "=v"(r) : "v"(x));
    return r;
}
__device__ __forceinline__ uint32 cvt_pk_bf16(float lo, float hi) {
    uint32 r;
    asm("v_cvt_pk_bf16_f32 %0, %1, %2" : "=v"(r) : "v"(lo), "v"(hi));
    return r;
}
// async 16B global -> LDS (wave-uniform LDS base + lane*16)
__device__ __forceinline__ void gload16(const u16* g, u16* l) {
    __builtin_amdgcn_global_load_lds((as1_u32*)(void*)g, (as3_u32*)l, 16, 0, 0);
}

// ---------------------------------------------------------------------------
// LayerNorm (fp32 in -> bf16 out). Two-source: row<split from in1 else in2.
// ---------------------------------------------------------------------------
__global__ __launch_bounds__(256) void ln_bf16_kernel(const float* __restrict__ in1,
                                                      const float* __restrict__ in2,
                                                      int split,
                                                      const float* __restrict__ g,
                                                      const float* __restrict__ b,
                                                      u16* __restrict__ out) {
    int row = blockIdx.x;
    const float* x = (row < split) ? in1 + (size_t)row * DIM
                                   : in2 + (size_t)(row - split) * DIM;
    u16* o = out + (size_t)row * DIM;
    int t = threadIdx.x;

    float v0 = x[t], v1 = x[t + 256], v2 = x[t + 512], v3 = x[t + 768];
    float s  = v0 + v1 + v2 + v3;
    float sq = v0 * v0 + v1 * v1 + v2 * v2 + v3 * v3;
    for (int off = 32; off; off >>= 1) {
        s  += __shfl_down(s, off);
        sq += __shfl_down(sq, off);
    }
    __shared__ float rs[4], rq[4];
    __shared__ float mean_s, rstd_s;
    int wid = t >> 6, lane = t & 63;
    if (lane == 0) { rs[wid] = s; rq[wid] = sq; }
    __syncthreads();
    if (t == 0) {
        float S = rs[0] + rs[1] + rs[2] + rs[3];
        float Q = rq[0] + rq[1] + rq[2] + rq[3];
        float m = S / (float)DIM;
        float var = Q / (float)DIM - m * m;
        mean_s = m;
        rstd_s = rsqrtf(var + 1e-5f);
    }
    __syncthreads();
    float m = mean_s, r = rstd_s;
    o[t]       = f2bf((v0 - m) * r * g[t]       + b[t]);
    o[t + 256] = f2bf((v1 - m) * r * g[t + 256] + b[t + 256]);
    o[t + 512] = f2bf((v2 - m) * r * g[t + 512] + b[t + 512]);
    o[t + 768] = f2bf((v3 - m) * r * g[t + 768] + b[t + 768]);
}

// ---------------------------------------------------------------------------
// All 5 weight transposes (fp32 [R][C] -> bf16 [C][R]) in one dispatch.
// ---------------------------------------------------------------------------
__global__ __launch_bounds__(256) void transpose_all(const float* __restrict__ qkv_w,
                                                     const float* __restrict__ out_w,
                                                     const float* __restrict__ w1,
                                                     const float* __restrict__ w3,
                                                     const float* __restrict__ w2,
                                                     u16* __restrict__ t_qkv,
                                                     u16* __restrict__ t_out,
                                                     u16* __restrict__ t_w1,
                                                     u16* __restrict__ t_w3,
                                                     u16* __restrict__ t_w2) {
    int bid = blockIdx.x;
    const float* in; u16* op; int R, C;
    if (bid < 3072)      { in = qkv_w; op = t_qkv; R = 1024; C = 3072; }
    else if (bid < 4096) { in = out_w; op = t_out; R = 1024; C = 1024; bid -= 3072; }
    else if (bid < 6912) { in = w1;    op = t_w1;  R = 1024; C = 2816; bid -= 4096; }
    else if (bid < 9728) { in = w3;    op = t_w3;  R = 1024; C = 2816; bid -= 6912; }
    else                 { in = w2;    op = t_w2;  R = 2816; C = 1024; bid -= 9728; }
    int nbx = C / 32;
    int c0 = (bid % nbx) * 32, r0 = (bid / nbx) * 32;

    __shared__ float tile[32][33];
    int tx = threadIdx.x & 31, ty = threadIdx.x >> 5;   // 32 x 8
#pragma unroll
    for (int i = 0; i < 32; i += 8)
        tile[ty + i][tx] = in[(size_t)(r0 + ty + i) * C + c0 + tx];
    __syncthreads();
#pragma unroll
    for (int i = 0; i < 32; i += 8)
        op[(size_t)(c0 + ty + i) * R + r0 + tx] = f2bf(tile[tx][ty + i]);
}

// ---------------------------------------------------------------------------
// bf16 MFMA GEMM v4 — m97 config: BK=64, global_load_lds(16B) into linear
// LDS with both-sides XOR swizzle, 2-barrier K-loop.
// C[M,N] = A[M,K] @ Bt[N,K]^T. Tile TM x 128, 256 threads (4 waves).
// RESMODE: 0 none; 1 += res fp32; 2 += row<LXX ? res : resB (split);
//          3 out = silu(res_bf16) * acc  (FFN w3+silu fusion).
// ROPE: fused RoPE on q/k column regions (QKV gemm). Rotation pairs
// (j, j+32) of each 64-col head block live in the SAME lane (ni 0<->2 at
// j=r, ni 1<->3 at j=r+16), so this is pure per-lane register math.
// q cols additionally scaled by 0.125*log2(e) (log2-domain attention).
// ---------------------------------------------------------------------------
template <int TM, bool OUTBF, bool BIAS, int RESMODE, int ROPE>
__global__ __launch_bounds__(256) void gemm3(const u16* __restrict__ A,
                                             const u16* __restrict__ Bt,
                                             const float* __restrict__ bias,
                                             const void* __restrict__ res,
                                             const float* __restrict__ resB,
                                             void* __restrict__ Cout,
                                             int M, int N, int K,
                                             const int* __restrict__ xpos,
                                             const int* __restrict__ opos) {
    constexpr int MI = TM / 32;             // m-fragments per wave (4 or 2)
    __shared__ u16 As[TM * 64];             // logical [TM][64], slot-swizzled
    __shared__ u16 Bs[128 * 64];
    int m0 = blockIdx.y * TM, n0 = blockIdx.x * 128;
    int t = threadIdx.x, lane = t & 63, w = t >> 6;
    int wr = (w >> 1) * (TM / 2), wc = (w & 1) * 64;
    int r = lane & 15, g = lane >> 4;

    // staging: thread t fetches row 32*s+(t>>3), PRE-SWIZZLED col-block
    // (t&7)^((t>>3)&7); HW writes LDS linearly at t*16B -> slot c^(row&7).
    int trow = t >> 3;
    int tcb  = (t & 7) ^ (trow & 7);
    const u16* ga = A  + (size_t)(m0 + trow) * K + tcb * 8;
    const u16* gb = Bt + (size_t)(n0 + trow) * K + tcb * 8;

    f32x4 acc[MI][4] = {};

    for (int k0 = 0; k0 < K; k0 += 64) {
#pragma unroll
        for (int s = 0; s < TM / 32; s++)
            gload16(ga + (size_t)(32 * s) * K + k0, &As[s * 2048 + w * 512]);
#pragma unroll
        for (int s = 0; s < 4; s++)
            gload16(gb + (size_t)(32 * s) * K + k0, &Bs[s * 2048 + w * 512]);
        __syncthreads();                     // drains vmcnt: LDS populated
#pragma unroll
        for (int kk = 0; kk < 2; kk++) {
            bf16x8 af[MI], bfv[4];
#pragma unroll
            for (int i = 0; i < MI; i++)
                af[i] = *(const bf16x8*)&As[(wr + i * 16 + r) * 64 + (((kk * 4 + g) ^ (r & 7)) * 8)];
#pragma unroll
            for (int i = 0; i < 4; i++)
                bfv[i] = *(const bf16x8*)&Bs[(wc + i * 16 + r) * 64 + (((kk * 4 + g) ^ (r & 7)) * 8)];
#pragma unroll
            for (int mi = 0; mi < MI; mi++)
#pragma unroll
                for (int ni = 0; ni < 4; ni++)
                    acc[mi][ni] = __builtin_amdgcn_mfma_f32_16x16x32_bf16(
                        af[mi], bfv[ni], acc[mi][ni], 0, 0, 0);
        }
        __syncthreads();                     // reads done before re-stage
    }

    float invA = 0.f, invB = 0.f;
    if (ROPE) {
        invA = exp2f(-0.41524101186092034f * (float)r);          // 10000^(-2j/64), j=r
        invB = exp2f(-0.41524101186092034f * (float)(r + 16));   // j=r+16
    }

#pragma unroll
    for (int mi = 0; mi < MI; mi++)
#pragma unroll
        for (int j = 0; j < 4; j++) {
            int row = m0 + wr + mi * 16 + g * 4 + j;
            float v[4];
#pragma unroll
            for (int ni = 0; ni < 4; ni++) {
                int col = n0 + wc + ni * 16 + r;
                v[ni] = acc[mi][ni][j];
                if (BIAS) v[ni] += bias[col];
            }
            if (ROPE) {
                int cb = n0 + wc;              // 64-aligned head block start
                if (cb < 2048) {               // q or k region only
                    float mul = (cb < 1024) ? 0.18033688f : 1.0f;  // 0.125*log2e on q
                    float pos = (row < LXX) ? (float)(*xpos + row)
                                            : (float)(*opos + (row - LXX));
                    float sA, cA, sB, cB;
                    __sincosf(pos * invA, &sA, &cA);
                    __sincosf(pos * invB, &sB, &cB);
                    float t0 = v[0], t1 = v[1], t2 = v[2], t3 = v[3];
                    v[0] = (t0 * cA - t2 * sA) * mul;
                    v[2] = (t2 * cA + t0 * sA) * mul;
                    v[1] = (t1 * cB - t3 * sB) * mul;
                    v[3] = (t3 * cB + t1 * sB) * mul;
                }
            }
#pragma unroll
            for (int ni = 0; ni < 4; ni++) {
                int col = n0 + wc + ni * 16 + r;
                float vv = v[ni];
                if (RESMODE == 1) vv += ((const float*)res)[(size_t)row * N + col];
                if (RESMODE == 2) vv += (row < LXX)
                        ? ((const float*)res)[(size_t)row * N + col]
                        : resB[(size_t)(row - LXX) * N + col];
                if (RESMODE == 3) {
                    float uv = bf2f(((const u16*)res)[(size_t)row * N + col]);
                    vv = (uv / (1.f + __expf(-uv))) * vv;
                }
                if (OUTBF) ((u16*)Cout)[(size_t)row * N + col] = f2bf(vv);
                else       ((float*)Cout)[(size_t)row * N + col] = vv;
            }
        }
}

// ---------------------------------------------------------------------------
// MFMA flash attention v5 (round-8 proven config, byte-identical): swapped
// QK^T, max-free exp2 softmax, cvt_pk packing, deferred l-reduction,
// reg-resident P. Grid (LQ/64, NH), 256 thr. KVBLK=64, XOR-swizzled LDS.
// MERGED: q0>=LXX uses Q2, stores bf16 to Ob; else fp32 to Of.
// RMW: read Of (fp32), add own result, store bf16 to Ob.
// ---------------------------------------------------------------------------
template <int CAUSAL, int MERGED, int RMW>
__global__ __launch_bounds__(256) void attn_v5(const u16* __restrict__ Q1,
                                               const u16* __restrict__ Q2,
                                               const u16* __restrict__ Kb,
                                               const u16* __restrict__ Vb,
                                               float* __restrict__ Of,
                                               u16* __restrict__ Ob,
                                               int LK) {
    __shared__ u16 Ks[64 * 64];
    __shared__ u16 Vt[64 * 64];
    int h = blockIdx.y;
    int q0 = blockIdx.x * 64;
    const u16* Qb = Q1;
    bool second = false;
    if (MERGED && q0 >= LXX) { Qb = Q2; second = true; q0 -= LXX; }
    int t = threadIdx.x, lane = t & 63, w = t >> 6;
    int r = lane & 15, g = lane >> 4;
    int hHD = h * HD;

    const u16* qp = Qb + (size_t)(q0 + w * 16 + r) * QKVW + hHD + g * 8;
    bf16x8 qf0 = *(const bf16x8*)qp;
    bf16x8 qf1 = *(const bf16x8*)(qp + 32);

    int kr = t >> 2, c0 = (t & 3) * 16;
    const u16* kg = Kb + hHD + c0;
    int d0 = (t & 31) * 2, kb = (t >> 5) * 8;
    const u16* vg = Vb + hHD + d0;
    int swk = ((kr >> 1) & 7) << 3;
    int swv = ((d0 >> 1) & 7) << 3;

    f32x4 o[4] = {};
    float l_run = 0.f;

    int nt = CAUSAL ? (q0 / 64 + 1) : (LK / 64);

    bf16x8 ka, ka2;
    uint32 vv[8];
    {
        size_t krow = (size_t)kr * QKVW;
        ka  = *(const bf16x8*)(kg + krow);
        ka2 = *(const bf16x8*)(kg + krow + 8);
#pragma unroll
        for (int kk = 0; kk < 8; kk++)
            vv[kk] = *(const uint32*)(vg + (size_t)(kb + kk) * QKVW);
    }

    for (int kt = 0; kt < nt; kt++) {
        int k0 = kt * 64;
        __syncthreads();
        // ---- stage tile (swizzled, all b128) ----
        *(bf16x8*)&Ks[kr * 64 + (c0 ^ swk)]       = ka;
        *(bf16x8*)&Ks[kr * 64 + ((c0 + 8) ^ swk)] = ka2;
        {
            uint4 lo4, hi4;
            lo4.x = __builtin_amdgcn_perm(vv[1], vv[0], 0x05040100);
            lo4.y = __builtin_amdgcn_perm(vv[3], vv[2], 0x05040100);
            lo4.z = __builtin_amdgcn_perm(vv[5], vv[4], 0x05040100);
            lo4.w = __builtin_amdgcn_perm(vv[7], vv[6], 0x05040100);
            hi4.x = __builtin_amdgcn_perm(vv[1], vv[0], 0x07060302);
            hi4.y = __builtin_amdgcn_perm(vv[3], vv[2], 0x07060302);
            hi4.z = __builtin_amdgcn_perm(vv[5], vv[4], 0x07060302);
            hi4.w = __builtin_amdgcn_perm(vv[7], vv[6], 0x07060302);
            *(uint4*)&Vt[d0 * 64 + (kb ^ swv)]       = lo4;
            *(uint4*)&Vt[(d0 + 1) * 64 + (kb ^ swv)] = hi4;
        }
        __syncthreads();
        // ---- prefetch next tile ----
        if (kt + 1 < nt) {
            int kn = k0 + 64;
            size_t krow = (size_t)(kn + kr) * QKVW;
            ka  = *(const bf16x8*)(kg + krow);
            ka2 = *(const bf16x8*)(kg + krow + 8);
#pragma unroll
            for (int kk = 0; kk < 8; kk++)
                vv[kk] = *(const uint32*)(vg + (size_t)(kn + kb + kk) * QKVW);
        }
        // ---- S^T = K @ Q^T (log2 domain) ----
        float xv[4][4];
        __builtin_amdgcn_s_setprio(1);
#pragma unroll
        for (int f = 0; f < 4; f++) {
            int row = f * 16 + r;
            int sw = ((row >> 1) & 7) << 3;
            bf16x8 klo = *(const bf16x8*)&Ks[row * 64 + ((g * 8) ^ sw)];
            bf16x8 khi = *(const bf16x8*)&Ks[row * 64 + ((32 + g * 8) ^ sw)];
            f32x4 z = {};
            z = __builtin_amdgcn_mfma_f32_16x16x32_bf16(klo, qf0, z, 0, 0, 0);
            z = __builtin_amdgcn_mfma_f32_16x16x32_bf16(khi, qf1, z, 0, 0, 0);
#pragma unroll
            for (int j = 0; j < 4; j++) xv[f][j] = z[j];
        }
        __builtin_amdgcn_s_setprio(0);
        if (CAUSAL && kt == nt - 1) {
            int qrow = q0 + w * 16 + r;
#pragma unroll
            for (int f = 0; f < 4; f++)
#pragma unroll
                for (int j = 0; j < 4; j++)
                    if (k0 + f * 16 + g * 4 + j > qrow) xv[f][j] = -1e30f;
        }
        // ---- max-free softmax: p = 2^s; defer cross-lane l-reduction ----
        float p_[4][4];
        float lt = 0.f;
#pragma unroll
        for (int f = 0; f < 4; f++)
#pragma unroll
            for (int j = 0; j < 4; j++) {
                p_[f][j] = fast_exp2(xv[f][j]);
                lt += p_[f][j];
            }
        l_run += lt;                        // per-lane partial; reduced at end
        // ---- pack P to bf16 pairs (single v_cvt_pk each) ----
        uint32 pk[4][2];
#pragma unroll
        for (int f = 0; f < 4; f++)
#pragma unroll
            for (int hh = 0; hh < 2; hh++)
                pk[f][hh] = cvt_pk_bf16(p_[f][2 * hh], p_[f][2 * hh + 1]);
        // ---- redistribute P^T (C/D layout) -> P A-frags ----
        uint32 paw0[4], paw1[4];
        bool gh = (g & 2) != 0;
#pragma unroll
        for (int c = 0; c < 4; c++) {
            int srcl = r + 16 * (2 * (g & 1) + (c >> 1));
            uint32 a0 = (uint32)__shfl((int)pk[0][c & 1], srcl, 64);
            uint32 a1 = (uint32)__shfl((int)pk[1][c & 1], srcl, 64);
            uint32 a2 = (uint32)__shfl((int)pk[2][c & 1], srcl, 64);
            uint32 a3 = (uint32)__shfl((int)pk[3][c & 1], srcl, 64);
            paw0[c] = gh ? a1 : a0;
            paw1[c] = gh ? a3 : a2;
        }
        union { uint32 u[4]; bf16x8 v; } pc0, pc1;
#pragma unroll
        for (int c = 0; c < 4; c++) { pc0.u[c] = paw0[c]; pc1.u[c] = paw1[c]; }
        bf16x8 pa0 = pc0.v, pa1 = pc1.v;
        // ---- O += P @ V ----
        __builtin_amdgcn_s_setprio(1);
#pragma unroll
        for (int df = 0; df < 4; df++) {
            int row = df * 16 + r;
            int sw = ((row >> 1) & 7) << 3;
            bf16x8 v0 = *(const bf16x8*)&Vt[row * 64 + ((g * 8) ^ sw)];
            bf16x8 v1 = *(const bf16x8*)&Vt[row * 64 + ((32 + g * 8) ^ sw)];
            o[df] = __builtin_amdgcn_mfma_f32_16x16x32_bf16(pa0, v0, o[df], 0, 0, 0);
            o[df] = __builtin_amdgcn_mfma_f32_16x16x32_bf16(pa1, v1, o[df], 0, 0, 0);
        }
        __builtin_amdgcn_s_setprio(0);
    }

    // ---- epilogue: reduce l across k-groups, normalize, store ----
    l_run += __shfl_xor(l_run, 16, 64);
    l_run += __shfl_xor(l_run, 32, 64);
    float lb[4];
#pragma unroll
    for (int j = 0; j < 4; j++) lb[j] = __shfl(l_run, (lane >> 4) * 4 + j, 64);
#pragma unroll
    for (int j = 0; j < 4; j++) lb[j] = 1.0f / lb[j];
#pragma unroll
    for (int df = 0; df < 4; df++)
#pragma unroll
        for (int j = 0; j < 4; j++) {
            float val = o[df][j] * lb[j];
            int row = q0 + w * 16 + g * 4 + j;
            int col = hHD + df * 16 + r;
            size_t idx = (size_t)row * DIM + col;
            if (MERGED) {
                if (second) Ob[idx] = f2bf(val);
                else        Of[idx] = val;
            } else if (RMW) {
                Ob[idx] = f2bf(val + Of[idx]);
            } else {
                Of[idx] = val;
            }
        }
}

// ---------------------------------------------------------------------------
// Orchestration
// ---------------------------------------------------------------------------
extern "C" void kernel_launch(void* const* d_in, const int* in_sizes, int n_in,
                              void* d_out, int out_size, void* d_ws, size_t ws_size,
                              hipStream_t stream) {
    const float* x     = (const float*)d_in[0];
    const float* ctx   = (const float*)d_in[1];
    const float* qkv_w = (const float*)d_in[2];
    const float* qkv_b = (const float*)d_in[3];
    const float* out_w = (const float*)d_in[4];
    const float* out_b = (const float*)d_in[5];
    const float* w1    = (const float*)d_in[6];
    const float* w3    = (const float*)d_in[7];
    const float* w2    = (const float*)d_in[8];
    const float* n1_g  = (const float*)d_in[9];
    const float* n1_b  = (const float*)d_in[10];
    const float* n2_g  = (const float*)d_in[11];
    const float* n2_b  = (const float*)d_in[12];
    const int*   ocp   = (const int*)d_in[13];
    const int*   xpos  = (const int*)d_in[15];

    float* out = (float*)d_out;                 // [4096][1024] fp32 (x_out|c_out)

    // workspace layout (u16 units) — ~93 MB total
    u16* wsp    = (u16*)d_ws;
    u16* wt_qkv = wsp;                                  // 3,145,728
    u16* wt_out = wt_qkv + (size_t)3072 * 1024;         // 1,048,576
    u16* wt_w1  = wt_out + (size_t)1024 * 1024;         // 2,883,584
    u16* wt_w3  = wt_w1  + (size_t)2816 * 1024;
    u16* wt_w2  = wt_w3  + (size_t)2816 * 1024;
    u16* lnbuf  = wt_w2  + (size_t)1024 * 2816;         // 6,291,456  [6144][1024]
    u16* qkvbf  = lnbuf  + (size_t)RTOT * DIM;          // 18,874,368 [6144][3072]
    float* attn_x = (float*)(qkvbf + (size_t)RTOT * QKVW);  // 2048*1024 fp32
    u16* h2_bf  = (u16*)(attn_x + (size_t)LXX * DIM);   // 4,194,304  [4096][1024]
    // aliases over dead regions
    u16* ax_bf = lnbuf;                          // [2048][1024], after QKV gemm
    u16* ac_bf = lnbuf + (size_t)LXX * DIM;      // contiguous with ax -> [4096][1024]
    u16* u_bf  = qkvbf;                          // [4096][2816], after attention
    u16* v_bf  = qkvbf + (size_t)4096 * HID;     // spills exactly into attn_x region

    // 1. all weight transposes, one dispatch
    transpose_all<<<12544, 256, 0, stream>>>(qkv_w, out_w, w1, w3, w2,
                                             wt_qkv, wt_out, wt_w1, wt_w3, wt_w2);

    // 2. LN1 over x|ctx -> bf16 [6144][1024]
    ln_bf16_kernel<<<RTOT, 256, 0, stream>>>(x, ctx, LXX, n1_g, n1_b, lnbuf);

    // 3. fused QKV GEMM with fused RoPE -> bf16 (rope kernel deleted)
    gemm3<128, true, true, 0, 1><<<dim3(QKVW / 128, RTOT / 128), 256, 0, stream>>>(
        lnbuf, wt_qkv, qkv_b, nullptr, nullptr, qkvbf, RTOT, QKVW, DIM, xpos, ocp);

    const u16* Qx = qkvbf;
    const u16* Kx = qkvbf + 1024;
    const u16* Vx = qkvbf + 2048;
    const u16* Kc = qkvbf + (size_t)LXX * QKVW + 1024;
    const u16* Vc = qkvbf + (size_t)LXX * QKVW + 2048;
    const u16* Qs = qkvbf + (size_t)(LXX + 2048) * QKVW;

    // 4. attentions: merged a1+a3 (a3 -> ac_bf direct); causal a2 RMW -> ax_bf
    attn_v5<0, 1, 0><<<dim3((LXX + 2048) / 64, NH), 256, 0, stream>>>(
        Qx, Qs, Kc, Vc, attn_x, ac_bf, LCC);
    attn_v5<1, 0, 1><<<dim3(LXX / 64, NH), 256, 0, stream>>>(
        Qx, nullptr, Kx, Vx, attn_x, ax_bf, LXX);

    // 5. merged out-proj: [4096][1024] attn @ out_w + bias + split residual -> out
    gemm3<64, false, true, 2, 0><<<dim3(DIM / 128, 4096 / 64), 256, 0, stream>>>(
        ax_bf, wt_out, out_b, x, ctx + (size_t)2048 * DIM, out, 4096, DIM, DIM,
        nullptr, nullptr);

    // 6. merged FFN over both streams (M=4096); silu fused into w3 epilogue
    ln_bf16_kernel<<<4096, 256, 0, stream>>>(out, out, 4096, n2_g, n2_b, h2_bf);
    gemm3<128, true, false, 0, 0><<<dim3(HID / 128, 4096 / 128), 256, 0, stream>>>(
        h2_bf, wt_w1, nullptr, nullptr, nullptr, u_bf, 4096, HID, DIM, nullptr, nullptr);
    gemm3<128, true, false, 3, 0><<<dim3(HID / 128, 4096 / 128), 256, 0, stream>>>(
        h2_bf, wt_w3, nullptr, u_bf, nullptr, v_bf, 4096, HID, DIM, nullptr, nullptr);
    gemm3<64, false, false, 1, 0><<<dim3(DIM / 128, 4096 / 64), 256, 0, stream>>>(
        v_bf, wt_w2, nullptr, out, nullptr, out, 4096, DIM, HID, nullptr, nullptr);
}